// Round 13
// baseline (203.083 us; speedup 1.0000x reference)
//
#include <hip/hip_runtime.h>

#define NB 2
#define SQ 512
#define SKV 4096
#define HID 1024
#define NH 16
#define NHK 4
#define NG 4
#define HD 64
#define EPSF 1e-6f
#define NSPLIT 4
#define RB (NB * NH * SQ)  // 16384 total q-rows

typedef short v8s __attribute__((ext_vector_type(8)));
typedef short v4s __attribute__((ext_vector_type(4)));
typedef float v4f __attribute__((ext_vector_type(4)));
typedef float v2f __attribute__((ext_vector_type(2)));

// branchless RTNE f32->bf16 bit-trick. NOT the (__bf16) HW cast: that emits a
// NaN-correct v_cmp/v_cndmask pair per element which serializes on VCC —
// measured +21us on attn_kernel (r8->r9 A/B, 61->82.5us).
static __device__ __forceinline__ short f2bf(float f) {
  unsigned u = __builtin_bit_cast(unsigned, f);
  u += 0x7FFFu + ((u >> 16) & 1u);
  return (short)(u >> 16);
}

// swizzled LDS fragment read: row-major [R][64] bf16 tile, 128B rows,
// byte ^= (row&7)<<4  (conflict-free for 16-row x 4-group b128 reads)
static __device__ __forceinline__ v8s lds_frag(const short* lds, int row, int kbyte) {
  return *(const v8s*)((const char*)lds + row * 128 + (kbyte ^ ((row & 7) << 4)));
}

// ---- 2-phase pipeline staging helpers: loads land in regs with NO dependent ops
// until stage_write after the compute block -> memory latency hides under compute. ----
template<int NIT>
static __device__ __forceinline__ void stage_load_f32(const float* src, int ld,
                                                      int r0, int c0, int t, v4f* regs) {
#pragma unroll
  for (int i = 0; i < NIT; ++i) {
    int flat = t * 8 + i * 2048;
    int row = flat >> 6, col = flat & 63;
    const float* p = src + (size_t)(r0 + row) * ld + c0 + col;
    regs[2 * i] = *(const v4f*)p;
    regs[2 * i + 1] = *(const v4f*)(p + 4);
  }
}

template<int NIT>
static __device__ __forceinline__ void stage_write_bf16(const v4f* regs, short* lds, int t) {
#pragma unroll
  for (int i = 0; i < NIT; ++i) {
    int flat = t * 8 + i * 2048;
    int row = flat >> 6, col = flat & 63;
    v4f a = regs[2 * i], b = regs[2 * i + 1];
    v8s v;
    v[0] = f2bf(a[0]); v[1] = f2bf(a[1]); v[2] = f2bf(a[2]); v[3] = f2bf(a[3]);
    v[4] = f2bf(b[0]); v[5] = f2bf(b[1]); v[6] = f2bf(b[2]); v[7] = f2bf(b[3]);
    *(v8s*)((char*)lds + row * 128 + ((col * 2) ^ ((row & 7) << 4))) = v;
  }
}

template<int NIT>
static __device__ __forceinline__ void stage_load_bf16(const short* src, int ld,
                                                       int r0, int c0, int t, v8s* regs) {
#pragma unroll
  for (int i = 0; i < NIT; ++i) {
    int flat = t * 8 + i * 2048;
    int row = flat >> 6, col = flat & 63;
    regs[i] = *(const v8s*)(src + (size_t)(r0 + row) * ld + c0 + col);
  }
}

template<int NIT>
static __device__ __forceinline__ void stage_write_raw(const v8s* regs, short* lds, int t) {
#pragma unroll
  for (int i = 0; i < NIT; ++i) {
    int flat = t * 8 + i * 2048;
    int row = flat >> 6, col = flat & 63;
    *(v8s*)((char*)lds + row * 128 + ((col * 2) ^ ((row & 7) << 4))) = regs[i];
  }
}

#define KV_ASZ (128 * 64)  // A region rows*64 (K/V branch)
#define Q_ASZ (64 * 64)    // A region (Q branch / wo)

// Unified Q/K/V projection, 640 blocks, XCD-aware mapping (r11) + single-barrier
// double-buffered pipeline (r12). smem blob [2][192*64] = 48KB -> 3 blocks/CU cap.
__global__ __launch_bounds__(256) void proj_all(const float* __restrict__ inputs,
                                                const float* __restrict__ latent,
                                                const float* __restrict__ wq,
                                                const float* __restrict__ wk,
                                                const float* __restrict__ wv,
                                                const float* __restrict__ qnw,
                                                const float* __restrict__ knw,
                                                short* __restrict__ Qb,
                                                short* __restrict__ Kb,
                                                short* __restrict__ Vtb) {
  __shared__ __align__(16) short smem[2][192 * 64];
  const int bid = blockIdx.x;
  const int t = threadIdx.x, lane = t & 63, w = t >> 6;
  const int l15 = lane & 15, g4 = lane >> 4;
  v4f acc[2][4] = {};

  if (bid < 512) {  // ---- K/V branch ----
    const int xcd = bid & 7, slot = bid >> 3;
    const int mblk = xcd * 8 + (slot >> 3);
    const int zh = slot & 7;
    const int z = zh & 1, head = zh >> 1;
    const int m0 = mblk * 128;
    const float* W = z ? wv : wk;
    v4f ar[8], br[4];
    stage_load_f32<4>(inputs, HID, m0, 0, t, ar);
    stage_load_f32<2>(W, HID, head * 64, 0, t, br);
    stage_write_bf16<4>(ar, &smem[0][0], t);
    stage_write_bf16<2>(br, &smem[0][KV_ASZ], t);
    for (int kt = 0; kt < 16; ++kt) {
      __syncthreads();
      const short* Acur = &smem[kt & 1][0];
      const short* Bcur = &smem[kt & 1][KV_ASZ];
      int kn = ((kt + 1) & 15) * 64;  // last iter re-loads tile 0 (uniform, discarded)
      stage_load_f32<4>(inputs, HID, m0, kn, t, ar);
      stage_load_f32<2>(W, HID, head * 64, kn, t, br);
      v8s af[2][2], bfr[4][2];
#pragma unroll
      for (int mf = 0; mf < 2; ++mf)
#pragma unroll
        for (int s = 0; s < 2; ++s)
          af[mf][s] = lds_frag(Acur, w * 32 + mf * 16 + l15, s * 64 + g4 * 16);
#pragma unroll
      for (int nf = 0; nf < 4; ++nf)
#pragma unroll
        for (int s = 0; s < 2; ++s)
          bfr[nf][s] = lds_frag(Bcur, nf * 16 + l15, s * 64 + g4 * 16);
#pragma unroll
      for (int mf = 0; mf < 2; ++mf)
#pragma unroll
        for (int nf = 0; nf < 4; ++nf)
#pragma unroll
          for (int s = 0; s < 2; ++s)
            acc[mf][nf] = __builtin_amdgcn_mfma_f32_16x16x32_bf16(af[mf][s], bfr[nf][s],
                                                                  acc[mf][nf], 0, 0, 0);
      if (kt + 1 < 16) {
        short* An = &smem[(kt + 1) & 1][0];
        stage_write_bf16<4>(ar, An, t);
        stage_write_bf16<2>(br, An + KV_ASZ, t);
      }
    }
    if (!z) {  // K: rmsnorm -> Kb [B,NHK,SKV,64]
      float wcol[4];
#pragma unroll
      for (int nf = 0; nf < 4; ++nf) wcol[nf] = knw[nf * 16 + l15];
#pragma unroll
      for (int mf = 0; mf < 2; ++mf)
#pragma unroll
        for (int j = 0; j < 4; ++j) {
          float ss = acc[mf][0][j] * acc[mf][0][j] + acc[mf][1][j] * acc[mf][1][j] +
                     acc[mf][2][j] * acc[mf][2][j] + acc[mf][3][j] * acc[mf][3][j];
#pragma unroll
          for (int msk = 1; msk < 16; msk <<= 1) ss += __shfl_xor(ss, msk);
          float sc = rsqrtf(ss * (1.0f / 64.0f) + EPSF);
          int m = m0 + w * 32 + mf * 16 + g4 * 4 + j;
          int b = m >> 12, sl = m & (SKV - 1);
          size_t base = ((size_t)(b * NHK + head) * SKV + sl) * 64;
#pragma unroll
          for (int nf = 0; nf < 4; ++nf)
            Kb[base + nf * 16 + l15] = f2bf(acc[mf][nf][j] * sc * wcol[nf]);
        }
    } else {  // V: transposed -> Vtb [B,NHK,64,SKV]
#pragma unroll
      for (int mf = 0; mf < 2; ++mf) {
        int m = m0 + w * 32 + mf * 16 + g4 * 4;
        int b = m >> 12, sl = m & (SKV - 1);
#pragma unroll
        for (int nf = 0; nf < 4; ++nf) {
          int d = nf * 16 + l15;
          v4s o;
#pragma unroll
          for (int j = 0; j < 4; ++j) o[j] = f2bf(acc[mf][nf][j]);
          *(v4s*)(Vtb + ((size_t)(b * NHK + head) * 64 + d) * SKV + sl) = o;
        }
      }
    }
  } else {  // ---- Q branch ----
    const int r = bid - 512;
    const int xcd = r & 7, slot = r >> 3;
    const int nblk = (slot & 1) | ((xcd & 3) << 1);
    const int mblk = ((slot >> 1) & 7) | ((xcd >> 2) << 3);
    const int m0 = mblk * 64;
    const int wr = w >> 1, wc = w & 1;
    v4f ar[4], br[8];
    stage_load_f32<2>(latent, HID, m0, 0, t, ar);
    stage_load_f32<4>(wq, HID, nblk * 128, 0, t, br);
    stage_write_bf16<2>(ar, &smem[0][0], t);
    stage_write_bf16<4>(br, &smem[0][Q_ASZ], t);
    for (int kt = 0; kt < 16; ++kt) {
      __syncthreads();
      const short* Acur = &smem[kt & 1][0];
      const short* Bcur = &smem[kt & 1][Q_ASZ];
      int kn = ((kt + 1) & 15) * 64;
      stage_load_f32<2>(latent, HID, m0, kn, t, ar);
      stage_load_f32<4>(wq, HID, nblk * 128, kn, t, br);
      v8s af[2][2], bfr[4][2];
#pragma unroll
      for (int mf = 0; mf < 2; ++mf)
#pragma unroll
        for (int s = 0; s < 2; ++s)
          af[mf][s] = lds_frag(Acur, wr * 32 + mf * 16 + l15, s * 64 + g4 * 16);
#pragma unroll
      for (int nf = 0; nf < 4; ++nf)
#pragma unroll
        for (int s = 0; s < 2; ++s)
          bfr[nf][s] = lds_frag(Bcur, wc * 64 + nf * 16 + l15, s * 64 + g4 * 16);
#pragma unroll
      for (int mf = 0; mf < 2; ++mf)
#pragma unroll
        for (int nf = 0; nf < 4; ++nf)
#pragma unroll
          for (int s = 0; s < 2; ++s)
            acc[mf][nf] = __builtin_amdgcn_mfma_f32_16x16x32_bf16(af[mf][s], bfr[nf][s],
                                                                  acc[mf][nf], 0, 0, 0);
      if (kt + 1 < 16) {
        short* An = &smem[(kt + 1) & 1][0];
        stage_write_bf16<2>(ar, An, t);
        stage_write_bf16<4>(br, An + Q_ASZ, t);
      }
    }
    const int head = nblk * 2 + wc;
    float wcol[4];
#pragma unroll
    for (int nf = 0; nf < 4; ++nf) wcol[nf] = qnw[nf * 16 + l15];
#pragma unroll
    for (int mf = 0; mf < 2; ++mf)
#pragma unroll
      for (int j = 0; j < 4; ++j) {
        float ss = acc[mf][0][j] * acc[mf][0][j] + acc[mf][1][j] * acc[mf][1][j] +
                   acc[mf][2][j] * acc[mf][2][j] + acc[mf][3][j] * acc[mf][3][j];
#pragma unroll
        for (int msk = 1; msk < 16; msk <<= 1) ss += __shfl_xor(ss, msk);
        float sc = rsqrtf(ss * (1.0f / 64.0f) + EPSF);
        int m = m0 + wr * 32 + mf * 16 + g4 * 4 + j;
        int b = m >> 9, sl = m & (SQ - 1);
        size_t base = ((size_t)(b * NH + head) * SQ + sl) * 64;
#pragma unroll
        for (int nf = 0; nf < 4; ++nf)
          Qb[base + nf * 16 + l15] = f2bf(acc[mf][nf][j] * sc * wcol[nf]);
      }
  }
}

// WO gemm, K-split x4, XCD-aware (xcd=bid&7=nblk), 2-phase pipelined.
__global__ __launch_bounds__(256) void wo_gemm(const short* __restrict__ Ab,
                                               const float* __restrict__ Wo,
                                               float* __restrict__ Wop) {
  __shared__ __align__(16) short smem[2][192 * 64];
  const int t = threadIdx.x, lane = t & 63, w = t >> 6;
  const int l15 = lane & 15, g4 = lane >> 4;
  const int wr = w >> 1, wc = w & 1;
  const int p = blockIdx.x;
  const int nblk = p & 7, slot = p >> 3;
  const int m0 = (slot & 15) * 64, n0 = nblk * 128, ks = slot >> 4;
  v4f acc[2][4] = {};
  v8s ar[2];
  v4f br[8];
  stage_load_bf16<2>(Ab, HID, m0, ks * 256, t, ar);
  stage_load_f32<4>(Wo, HID, n0, ks * 256, t, br);
  stage_write_raw<2>(ar, &smem[0][0], t);
  stage_write_bf16<4>(br, &smem[0][Q_ASZ], t);
  for (int kk = 0; kk < 4; ++kk) {
    __syncthreads();
    const short* Acur = &smem[kk & 1][0];
    const short* Bcur = &smem[kk & 1][Q_ASZ];
    int kn = ks * 256 + ((kk + 1) & 3) * 64;
    stage_load_bf16<2>(Ab, HID, m0, kn, t, ar);
    stage_load_f32<4>(Wo, HID, n0, kn, t, br);
    v8s af[2][2], bfr[4][2];
#pragma unroll
    for (int mf = 0; mf < 2; ++mf)
#pragma unroll
      for (int s = 0; s < 2; ++s)
        af[mf][s] = lds_frag(Acur, wr * 32 + mf * 16 + l15, s * 64 + g4 * 16);
#pragma unroll
    for (int nf = 0; nf < 4; ++nf)
#pragma unroll
      for (int s = 0; s < 2; ++s)
        bfr[nf][s] = lds_frag(Bcur, wc * 64 + nf * 16 + l15, s * 64 + g4 * 16);
#pragma unroll
    for (int mf = 0; mf < 2; ++mf)
#pragma unroll
      for (int nf = 0; nf < 4; ++nf)
#pragma unroll
        for (int s = 0; s < 2; ++s)
          acc[mf][nf] = __builtin_amdgcn_mfma_f32_16x16x32_bf16(af[mf][s], bfr[nf][s],
                                                                acc[mf][nf], 0, 0, 0);
    if (kk + 1 < 4) {
      short* An = &smem[(kk + 1) & 1][0];
      stage_write_raw<2>(ar, An, t);
      stage_write_bf16<4>(br, An + Q_ASZ, t);
    }
  }
  float* C = Wop + (size_t)ks * HID * NB * SQ;
#pragma unroll
  for (int mf = 0; mf < 2; ++mf)
#pragma unroll
    for (int j = 0; j < 4; ++j) {
      int m = m0 + wr * 32 + mf * 16 + g4 * 4 + j;
#pragma unroll
      for (int nf = 0; nf < 4; ++nf)
        C[(size_t)m * HID + n0 + wc * 64 + nf * 16 + l15] = acc[mf][nf][j];
    }
}

// Sum 4 K-split partials -> d_out f32
__global__ __launch_bounds__(256) void wo_reduce(const float* __restrict__ Wop,
                                                 float* __restrict__ out) {
  int idx = (blockIdx.x * 256 + threadIdx.x) * 4;
  v4f s = *(const v4f*)(Wop + idx);
#pragma unroll
  for (int ks = 1; ks < 4; ++ks) {
    v4f p = *(const v4f*)(Wop + (size_t)ks * HID * NB * SQ + idx);
    s[0] += p[0]; s[1] += p[1]; s[2] += p[2]; s[3] += p[3];
  }
  *(v4f*)(out + idx) = s;
}

// Flash attention, KV-split, KVBLK=128, batched softmax. r12->r13 changes:
// (1) XCD-aware decode: hkb=id&7 -> (b,hk); all 128 blocks (4 splits x 32 qt) of one
//     (b,hk) land on ONE XCD -> K+V (1MB) + Q (256KB) L2-resident after first touch.
// (2) 2-phase staging: next K/V tiles prefetched into regs during compute (write-late
//     at loop top). Per-block arithmetic identical to r12 -> bitwise-identical output.
__global__ __launch_bounds__(256) void attn_kernel(const short* __restrict__ Qb,
                                                   const short* __restrict__ Kb,
                                                   const short* __restrict__ Vt,
                                                   float* __restrict__ Op,
                                                   float* __restrict__ Ml) {
  __shared__ __align__(16) short Ksm[2][64 * 64];
  __shared__ __align__(16) short Vsm[2][64 * 64];
  __shared__ __align__(16) short Psm[4][16 * 64];
  int id = blockIdx.x;
  int hkb = id & 7, qt = (id >> 3) & 31, sp = id >> 8;
  int hk = hkb & 3, b = hkb >> 2;
  int t = threadIdx.x, w = t >> 6, lane = t & 63;
  int l15 = lane & 15, g4 = lane >> 4;
  int h = hk * NG + w;

  const short* qbase = Qb + (((size_t)(b * NH + h)) * SQ + qt * 16) * 64;
  v8s aq[2];
#pragma unroll
  for (int s = 0; s < 2; ++s)
    aq[s] = *(const v8s*)(qbase + (size_t)l15 * 64 + s * 32 + g4 * 8);

  const short* kbase = Kb + ((size_t)(b * NHK + hk)) * SKV * 64;
  const short* vbase = Vt + ((size_t)(b * NHK + hk)) * 64 * SKV;
  char* pbase = (char*)&Psm[w][0];

  v4f acco[4] = {};
  float mrow[4], lrow[4];
#pragma unroll
  for (int r = 0; r < 4; ++r) { mrow[r] = -__builtin_inff(); lrow[r] = 0.f; }

  const int NT = SKV / NSPLIT / 128;  // 8
  const int KV0 = sp * (SKV / NSPLIT);
  v8s kr[4], vr[4];
  stage_load_bf16<2>(kbase, 64, KV0, 0, t, kr);
  stage_load_bf16<2>(kbase, 64, KV0 + 64, 0, t, kr + 2);
  stage_load_bf16<2>(vbase, SKV, 0, KV0, t, vr);
  stage_load_bf16<2>(vbase, SKV, 0, KV0 + 64, t, vr + 2);
  for (int kt = 0; kt < NT; ++kt) {
    __syncthreads();
    stage_write_raw<2>(kr, Ksm[0], t);
    stage_write_raw<2>(kr + 2, Ksm[1], t);
    stage_write_raw<2>(vr, Vsm[0], t);
    stage_write_raw<2>(vr + 2, Vsm[1], t);
    __syncthreads();
    if (kt + 1 < NT) {  // prefetch next tile; latency hides under compute below
      int kv1 = KV0 + (kt + 1) * 128;
      stage_load_bf16<2>(kbase, 64, kv1, 0, t, kr);
      stage_load_bf16<2>(kbase, 64, kv1 + 64, 0, t, kr + 2);
      stage_load_bf16<2>(vbase, SKV, 0, kv1, t, vr);
      stage_load_bf16<2>(vbase, SKV, 0, kv1 + 64, t, vr + 2);
    }

    v4f accs[8] = {};
#pragma unroll
    for (int hf = 0; hf < 2; ++hf)
#pragma unroll
      for (int f = 0; f < 4; ++f)
#pragma unroll
        for (int s = 0; s < 2; ++s) {
          v8s bk = lds_frag(Ksm[hf], f * 16 + l15, s * 64 + g4 * 16);
          accs[hf * 4 + f] =
              __builtin_amdgcn_mfma_f32_16x16x32_bf16(aq[s], bk, accs[hf * 4 + f], 0, 0, 0);
        }

    float tm[4];
#pragma unroll
    for (int r = 0; r < 4; ++r) {
      float m01 = fmaxf(accs[0][r], accs[1][r]), m23 = fmaxf(accs[2][r], accs[3][r]);
      float m45 = fmaxf(accs[4][r], accs[5][r]), m67 = fmaxf(accs[6][r], accs[7][r]);
      tm[r] = fmaxf(fmaxf(m01, m23), fmaxf(m45, m67));
    }
#pragma unroll
    for (int msk = 1; msk < 16; msk <<= 1)
#pragma unroll
      for (int r = 0; r < 4; ++r)
        tm[r] = fmaxf(tm[r], __shfl_xor(tm[r], msk));
    float al[4];
#pragma unroll
    for (int r = 0; r < 4; ++r) {
      float mn = fmaxf(mrow[r], tm[r]);
      al[r] = __expf(mrow[r] - mn);
      mrow[r] = mn;
    }
    float rs[4] = {0.f, 0.f, 0.f, 0.f};
#pragma unroll
    for (int f = 0; f < 8; ++f)
#pragma unroll
      for (int r = 0; r < 4; ++r) {
        accs[f][r] = __expf(accs[f][r] - mrow[r]);
        rs[r] += accs[f][r];
      }
#pragma unroll
    for (int msk = 1; msk < 16; msk <<= 1)
#pragma unroll
      for (int r = 0; r < 4; ++r) rs[r] += __shfl_xor(rs[r], msk);
#pragma unroll
    for (int r = 0; r < 4; ++r) lrow[r] = lrow[r] * al[r] + rs[r];
#pragma unroll
    for (int fd = 0; fd < 4; ++fd)
#pragma unroll
      for (int r = 0; r < 4; ++r) acco[fd][r] *= al[r];

#pragma unroll
    for (int hf = 0; hf < 2; ++hf) {
#pragma unroll
      for (int f = 0; f < 4; ++f)
#pragma unroll
        for (int r = 0; r < 4; ++r) {
          int row = g4 * 4 + r;
          int colB = (f * 16 + l15) * 2;
          *(short*)(pbase + row * 128 + (colB ^ ((row & 7) << 4))) = f2bf(accs[hf * 4 + f][r]);
        }
      asm volatile("s_waitcnt lgkmcnt(0)" ::: "memory");
      __builtin_amdgcn_sched_barrier(0);
      v8s pa[2];
#pragma unroll
      for (int s = 0; s < 2; ++s)
        pa[s] = *(const v8s*)(pbase + l15 * 128 + ((s * 64 + g4 * 16) ^ ((l15 & 7) << 4)));
      asm volatile("s_waitcnt lgkmcnt(0)" ::: "memory");
      __builtin_amdgcn_sched_barrier(0);
#pragma unroll
      for (int fd = 0; fd < 4; ++fd)
#pragma unroll
        for (int s = 0; s < 2; ++s) {
          v8s vb = lds_frag(Vsm[hf], fd * 16 + l15, s * 64 + g4 * 16);
          acco[fd] = __builtin_amdgcn_mfma_f32_16x16x32_bf16(pa[s], vb, acco[fd], 0, 0, 0);
        }
    }
  }

  size_t rowbase = ((size_t)b * NH + h) * SQ + qt * 16;
#pragma unroll
  for (int fd = 0; fd < 4; ++fd)
#pragma unroll
    for (int r = 0; r < 4; ++r) {
      int row = g4 * 4 + r;
      Op[((size_t)sp * RB + rowbase + row) * 64 + fd * 16 + l15] = acco[fd][r];
    }
  if (l15 == 0) {
#pragma unroll
    for (int r = 0; r < 4; ++r) {
      int row = g4 * 4 + r;
      v2f ml; ml[0] = mrow[r]; ml[1] = lrow[r];
      *(v2f*)(Ml + ((size_t)sp * RB + rowbase + row) * 2) = ml;
    }
  }
}

// Merge NSPLIT partials -> Ab bf16 [B, SQ, H*64]
__global__ __launch_bounds__(256) void merge_attn(const float* __restrict__ Op,
                                                  const float* __restrict__ Ml,
                                                  short* __restrict__ Ab) {
  int idx = blockIdx.x * 256 + threadIdx.x;  // RB*64 total
  int d = idx & 63, row = idx >> 6;
  float ms[NSPLIT], ls[NSPLIT];
  float M = -__builtin_inff();
#pragma unroll
  for (int s = 0; s < NSPLIT; ++s) {
    v2f ml = *(const v2f*)(Ml + ((size_t)s * RB + row) * 2);
    ms[s] = ml[0]; ls[s] = ml[1];
    M = fmaxf(M, ms[s]);
  }
  float L = 0.f, o = 0.f;
#pragma unroll
  for (int s = 0; s < NSPLIT; ++s) {
    float wgt = __expf(ms[s] - M);
    L += ls[s] * wgt;
    o += wgt * Op[((size_t)s * RB + row) * 64 + d];
  }
  int b = row >> 13;
  int hh = (row >> 9) & 15;
  int sq = row & 511;
  Ab[((size_t)(b * SQ + sq)) * HID + hh * 64 + d] = f2bf(o / L);
}

extern "C" void kernel_launch(void* const* d_in, const int* in_sizes, int n_in,
                              void* d_out, int out_size, void* d_ws, size_t ws_size,
                              hipStream_t stream) {
  const float* inputs = (const float*)d_in[0];  // [B,SKV,1024]
  const float* latent = (const float*)d_in[1];  // [B,SQ,1024]
  const float* wq = (const float*)d_in[2];      // [1024,1024]
  const float* wk = (const float*)d_in[3];      // [256,1024]
  const float* wv = (const float*)d_in[4];      // [256,1024]
  const float* wo = (const float*)d_in[5];      // [1024,1024]
  const float* qnw = (const float*)d_in[6];     // [64]
  const float* knw = (const float*)d_in[7];     // [64]

  char* ws = (char*)d_ws;
  float* Op  = (float*)(ws);                    // 16 MB  [NSPLIT, RB, 64] (dead after merge)
  float* Wop = (float*)(ws);                    // 16 MB  [4,1024,1024] wo partials (reuses Op)
  float* Ml  = (float*)(ws + 16777216);         // 0.5 MB [NSPLIT, RB, 2]
  short* Qb  = (short*)(ws + 17825792);         // 2 MB   [B,NH,SQ,64]
  short* Kb  = (short*)(ws + 19922944);         // 4 MB   [B,NHK,SKV,64]
  short* Vtb = (short*)(ws + 24117248);         // 4 MB   [B,NHK,64,SKV]
  short* Ab  = (short*)(ws + 28311552);         // 2 MB   [B,SQ,1024]

  proj_all<<<640, 256, 0, stream>>>(inputs, latent, wq, wk, wv, qnw, knw, Qb, Kb, Vtb);
  attn_kernel<<<256 * NSPLIT, 256, 0, stream>>>(Qb, Kb, Vtb, Op, Ml);
  merge_attn<<<RB * 64 / 256, 256, 0, stream>>>(Op, Ml, Ab);
  wo_gemm<<<512, 256, 0, stream>>>(Ab, wo, Wop);
  wo_reduce<<<1024, 256, 0, stream>>>(Wop, (float*)d_out);
}